// Round 11
// baseline (106.440 us; speedup 1.0000x reference)
//
#include <hip/hip_runtime.h>

// EncoderBlock, two-stage, BN block-local, barrier-free K-loop, 2 BLOCKS/CU:
//  K0 (prep): x (16MB fp32) -> xb bf16, skewed batch stride (8320 elems).
//  K1 (fused): gather(xb) -> GEMM slice (M=512 x N=32 @ K=512) + bias ->
//              block-local BN over 512 rows -> SiLU -> fp32 out.
// R10 postmortem: latency depth, barriers, and channel-decamping all null;
// fused GEMM stuck ~33us with every pipe idle. Last unvaried axis: ONE
// 16-wave block per CU serializes prologue (cold-W B-stage behind a block
// barrier), K-loop, and epilogue for the whole CU. This round: same grid
// (256 = 64 o x 4 col-slices), 512-thread blocks (8 waves x 64 rows, 4
// m-frags/wave), TWO independent blocks per CU (16 waves/CU unchanged) so
// one block's stage/epilogue/tail overlaps the other's K-loop.
// A: direct-to-register depth-2 ring; B: 32.5KB LDS panel staged once;
// per-wave K-rotation (wave w starts at step 2w); no K-loop barriers; no
// cross-block sync anywhere (R2/R4/R5: 50-80us cost).

typedef __attribute__((ext_vector_type(8))) __bf16 bf16x8;
typedef __attribute__((ext_vector_type(4))) float  f32x4;

#define FEAT 8192
#define XROWP 8320           // skewed xb batch stride in elems (16640B)
#define LDSB 520             // B panel e-row stride in bf16 (512 + 8 pad)
#define NX8  524288          // x chunks of 8 floats (512*64*128/8)

__global__ __launch_bounds__(256)
void cvt_kernel(const float* __restrict__ x, __bf16* __restrict__ xb)
{
    const int stride = gridDim.x * blockDim.x;
    for (int c = blockIdx.x * blockDim.x + threadIdx.x; c < NX8; c += stride) {
        const int b = c >> 10;          // 1024 8-elem chunks per batch row
        const int j = c & 1023;
        const f32x4 v0 = *(const f32x4*)(x + c * 8);
        const f32x4 v1 = *(const f32x4*)(x + c * 8 + 4);
        bf16x8 o;
#pragma unroll
        for (int jj = 0; jj < 4; ++jj) {
            o[jj]     = (__bf16)v0[jj];
            o[jj + 4] = (__bf16)v1[jj];
        }
        *(bf16x8*)(xb + (size_t)b * XROWP + j * 8) = o;
    }
}

__global__ __launch_bounds__(512, 4)
void fused_encoder(const __bf16* __restrict__ xb, const float* __restrict__ W,
                   const float* __restrict__ bias, const float* __restrict__ gamma,
                   const float* __restrict__ beta, const int* __restrict__ idxp,
                   float* __restrict__ out)
{
    __shared__ __bf16 Bpan[32 * LDSB];   // 32.5 KiB: B^T panel [e][k]
    __shared__ float Sred[8][32];
    __shared__ float Qred[8][32];
    __shared__ float sscale[32];
    __shared__ float sshift[32];

    // XCD-aware decode: 4 col-slices of one o share an XCD (A panel L2 reuse)
    const int bid = blockIdx.x;
    const int o   = ((bid >> 5) << 3) | (bid & 7);
    const int es  = (bid >> 3) & 3;
    const int e0  = es * 32;

    const int tid  = threadIdx.x;
    const int wave = tid >> 6;          // 0..7 -> rows wave*64 .. +63
    const int lane = tid & 63;
    const int lam  = lane & 15;
    const int quad = lane >> 4;

    // gathered row ids as 4 NAMED scalars (branchless select, no scratch)
    const int r0 = idxp[o * 4 + 0];
    const int r1 = idxp[o * 4 + 1];
    const int r2 = idxp[o * 4 + 2];
    const int r3 = idxp[o * 4 + 3];

    auto rowOf = [&](const int kc) -> int {
        const int kidx = kc >> 2;
        const int ra = (kidx & 1) ? r1 : r0;
        const int rb = (kidx & 1) ? r3 : r2;
        return (kidx & 2) ? rb : ra;
    };

    // A: per-lane row bases for the 4 m-fragments (rows wave*64 + mi*16 + lam)
    const __bf16* xr0 = xb + (size_t)(wave * 64 +  0 + lam) * XROWP;
    const __bf16* xr1 = xb + (size_t)(wave * 64 + 16 + lam) * XROWP;
    const __bf16* xr2 = xb + (size_t)(wave * 64 + 32 + lam) * XROWP;
    const __bf16* xr3 = xb + (size_t)(wave * 64 + 48 + lam) * XROWP;

    // depth-2 A register ring (named stages; mi indices static under unroll)
    bf16x8 sa0[4], sa1[4];
    auto loadA = [&](bf16x8 (&S)[4], const int kc) {
        const int r   = rowOf(kc);
        const int off = r * 128 + (kc & 3) * 32 + quad * 8;
        S[0] = *(const bf16x8*)(xr0 + off);
        S[1] = *(const bf16x8*)(xr1 + off);
        S[2] = *(const bf16x8*)(xr2 + off);
        S[3] = *(const bf16x8*)(xr3 + off);
    };

    // per-wave K-phase rotation: wave w starts at step 2w (order-independent)
    const int kk0 = wave * 2;
    loadA(sa0, kk0 & 15);
    loadA(sa1, (kk0 + 1) & 15);

    // ---- one-time B panel stage: Bpan[e][k] = bf16(W[k-global][e0+e]) ----
    {
        const int e  = tid & 31;
        const int k0 = (tid >> 5) * 32;      // 16 chunks x 32 k
        float v[32];
#pragma unroll
        for (int j = 0; j < 32; ++j) {
            const int k = k0 + j;
            v[j] = W[(((o * 4 + (k >> 7)) * 128) + (k & 127)) * 128 + e0 + e];
        }
#pragma unroll
        for (int c = 0; c < 4; ++c) {
            bf16x8 w;
#pragma unroll
            for (int j = 0; j < 8; ++j) w[j] = (__bf16)v[c * 8 + j];
            *(bf16x8*)&Bpan[e * LDSB + k0 + c * 8] = w;
        }
    }

    const f32x4 zero4 = {0.f, 0.f, 0.f, 0.f};
    f32x4 acc[4][2];
#pragma unroll
    for (int mi = 0; mi < 4; ++mi)
#pragma unroll
        for (int ni = 0; ni < 2; ++ni) acc[mi][ni] = zero4;

    __syncthreads();            // B panel visible; only barrier before epilogue

    // B fragment double-buffer (depth-2, LDS latency hidden under MFMA)
    bf16x8 bq0[2], bq1[2];
    bq0[0] = *(const bf16x8*)&Bpan[lam        * LDSB + kk0 * 32 + quad * 8];
    bq0[1] = *(const bf16x8*)&Bpan[(16 + lam) * LDSB + kk0 * 32 + quad * 8];

    // ---- barrier-free rotated K-loop: 16 steps of 32 k ----
#pragma unroll
    for (int i = 0; i < 16; ++i) {
        if ((i & 1) == 0) {
            if (i + 1 < 16) {
                const int kn = (kk0 + i + 1) & 15;
                bq1[0] = *(const bf16x8*)&Bpan[lam        * LDSB + kn * 32 + quad * 8];
                bq1[1] = *(const bf16x8*)&Bpan[(16 + lam) * LDSB + kn * 32 + quad * 8];
            }
#pragma unroll
            for (int mi = 0; mi < 4; ++mi) {
                acc[mi][0] = __builtin_amdgcn_mfma_f32_16x16x32_bf16(sa0[mi], bq0[0], acc[mi][0], 0, 0, 0);
                acc[mi][1] = __builtin_amdgcn_mfma_f32_16x16x32_bf16(sa0[mi], bq0[1], acc[mi][1], 0, 0, 0);
            }
            if (i + 2 < 16) loadA(sa0, (kk0 + i + 2) & 15);
        } else {
            if (i + 1 < 16) {
                const int kn = (kk0 + i + 1) & 15;
                bq0[0] = *(const bf16x8*)&Bpan[lam        * LDSB + kn * 32 + quad * 8];
                bq0[1] = *(const bf16x8*)&Bpan[(16 + lam) * LDSB + kn * 32 + quad * 8];
            }
#pragma unroll
            for (int mi = 0; mi < 4; ++mi) {
                acc[mi][0] = __builtin_amdgcn_mfma_f32_16x16x32_bf16(sa1[mi], bq1[0], acc[mi][0], 0, 0, 0);
                acc[mi][1] = __builtin_amdgcn_mfma_f32_16x16x32_bf16(sa1[mi], bq1[1], acc[mi][1], 0, 0, 0);
            }
            if (i + 2 < 16) loadA(sa1, (kk0 + i + 2) & 15);
        }
    }

    // ---- bias ----
    float bvals[2];
#pragma unroll
    for (int ni = 0; ni < 2; ++ni)
        bvals[ni] = bias[o * 128 + e0 + ni * 16 + lam];
#pragma unroll
    for (int mi = 0; mi < 4; ++mi)
#pragma unroll
        for (int ni = 0; ni < 2; ++ni)
#pragma unroll
            for (int rr = 0; rr < 4; ++rr) acc[mi][ni][rr] += bvals[ni];

    // ---- BN stats: block-local (block owns all 512 rows of its 32 cols) ----
#pragma unroll
    for (int ni = 0; ni < 2; ++ni) {
        float s = 0.f, q = 0.f;
#pragma unroll
        for (int mi = 0; mi < 4; ++mi)
#pragma unroll
            for (int rr = 0; rr < 4; ++rr) {
                const float v = acc[mi][ni][rr];
                s += v; q += v * v;
            }
        s += __shfl_xor(s, 16); s += __shfl_xor(s, 32);   // over 4 quads -> 64 rows
        q += __shfl_xor(q, 16); q += __shfl_xor(q, 32);
        if (quad == 0) {
            Sred[wave][ni * 16 + lam] = s;
            Qred[wave][ni * 16 + lam] = q;
        }
    }
    __syncthreads();

    if (tid < 32) {
        float s = 0.f, q = 0.f;
#pragma unroll
        for (int w = 0; w < 8; ++w) {
            s += Sred[w][tid];
            q += Qred[w][tid];
        }
        const float mean = s * (1.0f / 512.0f);
        const float var  = q * (1.0f / 512.0f) - mean * mean;
        const float rstd = rsqrtf(var + 1e-5f);
        const float sc   = rstd * gamma[o * 128 + e0 + tid];
        sscale[tid] = sc;
        sshift[tid] = beta[o * 128 + e0 + tid] - mean * sc;
    }
    __syncthreads();

    // ---- normalize + SiLU in-register, store fp32 ----
#pragma unroll
    for (int mi = 0; mi < 4; ++mi) {
        const int rowb = wave * 64 + mi * 16 + quad * 4;
#pragma unroll
        for (int ni = 0; ni < 2; ++ni) {
            const int col = ni * 16 + lam;
            const float sc = sscale[col];
            const float sh = sshift[col];
#pragma unroll
            for (int rr = 0; rr < 4; ++rr) {
                const float xn = acc[mi][ni][rr] * sc + sh;
                const float sg = 1.0f / (1.0f + __expf(-xn));
                out[(rowb + rr) * FEAT + o * 128 + e0 + col] = xn * sg;
            }
        }
    }
}

extern "C" void kernel_launch(void* const* d_in, const int* in_sizes, int n_in,
                              void* d_out, int out_size, void* d_ws, size_t ws_size,
                              hipStream_t stream)
{
    const float* x     = (const float*)d_in[0];
    const float* W     = (const float*)d_in[1];
    const float* bias  = (const float*)d_in[2];
    const float* gamma = (const float*)d_in[3];
    const float* beta  = (const float*)d_in[4];
    const int*   idx   = (const int*)d_in[5];
    float* out = (float*)d_out;

    __bf16* xb = (__bf16*)d_ws;              // 512*8320*2B = 8.5 MiB

    cvt_kernel<<<dim3(512), dim3(256), 0, stream>>>(x, xb);
    fused_encoder<<<dim3(256), dim3(512), 0, stream>>>(
        xb, W, bias, gamma, beta, idx, out);
}